// Round 9
// baseline (354.255 us; speedup 1.0000x reference)
//
#include <hip/hip_runtime.h>
#include <math.h>

// Problem dims
constexpr int T0n = 2048;   // tokens
constexpr int Dn  = 2048;   // hidden
constexpr int En  = 256;    // experts
constexpr int Gn  = 8;      // groups
constexpr int EGn = 32;     // experts per group
constexpr int Rn  = 64;     // tucker rank
constexpr int In  = 1408;   // intermediate

constexpr int NROWS = T0n * 8;    // 16384 dispatched rows
constexpr int SEGCAP = NROWS;     // per-group segment capacity in rseg
constexpr int KSPLIT = 4;         // router split-K factor

typedef __attribute__((ext_vector_type(8))) short s8v;    // 8 bf16
typedef __attribute__((ext_vector_type(4))) float f4v;    // 4 fp32
#define MFMA16(a, b, c) __builtin_amdgcn_mfma_f32_16x16x32_bf16(a, b, c, 0, 0, 0)

__device__ __forceinline__ unsigned short f2bf(float x) {
  unsigned int u = __float_as_uint(x);
  unsigned int r = (u + 0x7FFFu + ((u >> 16) & 1u)) >> 16;
  return (unsigned short)r;
}

// ---------------------------------------------------------------------------
// Fused batched transpose+convert for 6 weight tensors:
// src f32 [batch][rows][cols] -> dst bf16 [batch][cols][rows].
// (C_gate/C_up/C_down now transposed in-kernel by their single consumer.)
// ---------------------------------------------------------------------------
struct TD { const float* src; unsigned short* dst; int rows, cols, nbx, per_batch, base; };
struct TD6 { TD t[6]; };

__global__ __launch_bounds__(256) void k_tcvt6(TD6 D) {
  __shared__ float tbuf[32][33];
  int id = blockIdx.x;
  int ti = 0;
#pragma unroll
  for (int i = 1; i < 6; ++i) ti = (id >= D.t[i].base) ? i : ti;
  TD d = D.t[ti];
  int local = id - d.base;
  int bz = local / d.per_batch;
  int rem = local - bz * d.per_batch;
  int by = rem / d.nbx;
  int bx = rem - by * d.nbx;

  size_t boff = (size_t)bz * d.rows * d.cols;
  const float* src = d.src + boff;
  unsigned short* dst = d.dst + boff;
  int c0 = bx * 32, r0 = by * 32;
  int tx = threadIdx.x & 31, ty = threadIdx.x >> 5;   // ty 0..7
  for (int i = ty; i < 32; i += 8)
    tbuf[i][tx] = src[(size_t)(r0 + i) * d.cols + c0 + tx];
  __syncthreads();
  for (int i = ty; i < 32; i += 8)
    dst[(size_t)(c0 + i) * d.rows + r0 + tx] = f2bf(tbuf[tx][i]);
}

// ---------------------------------------------------------------------------
// Router logits, split-K, FP64 accumulation (exact expert ordering).
// FP64 LDS with conflict-free b64 layout: thread (ty,tx) reads 4 A-values at
// m=ty+16i and 4 B-values at n=tx+16j — each ds_read_b64 hits 16 distinct
// even-word addresses (every bank <=1x, same-ty/tx lanes broadcast). Converts
// f32->f64 ONCE at staging (R8's per-kk cvt was 1/3 of VALU issue).
// Side-channel: blockIdx.x==0 blocks emit Hb (bf16 H) while loading A.
// grid (E/64, T0/64, KSPLIT=4).
// ---------------------------------------------------------------------------
__global__ __launch_bounds__(256) void k_router_part(
    const float* __restrict__ A, const float* __restrict__ B,
    double* __restrict__ part, unsigned short* __restrict__ Hb) {
  __shared__ double Asd[32][66];   // [k][m], stride 66 doubles
  __shared__ double Bsd[32][66];   // [k][n]
  const int m0 = blockIdx.y * 64, n0 = blockIdx.x * 64;
  const int kbeg = blockIdx.z * (Dn / KSPLIT);   // 512-wide K slice
  const int tid = threadIdx.x;
  const int ty = tid >> 4, tx = tid & 15;
  const int lm = tid & 63, lk8 = (tid >> 6) * 8;   // A loader
  const int br = tid >> 3, bc = (tid & 7) * 8;     // B loader
  const bool emitH = (blockIdx.x == 0);

  double acc[4][4] = {};

  for (int k0 = kbeg; k0 < kbeg + Dn / KSPLIT; k0 += 32) {
    float4 a0 = *(const float4*)&A[(size_t)(m0 + lm) * Dn + k0 + lk8];
    float4 a1 = *(const float4*)&A[(size_t)(m0 + lm) * Dn + k0 + lk8 + 4];
    Asd[lk8 + 0][lm] = (double)a0.x; Asd[lk8 + 1][lm] = (double)a0.y;
    Asd[lk8 + 2][lm] = (double)a0.z; Asd[lk8 + 3][lm] = (double)a0.w;
    Asd[lk8 + 4][lm] = (double)a1.x; Asd[lk8 + 5][lm] = (double)a1.y;
    Asd[lk8 + 6][lm] = (double)a1.z; Asd[lk8 + 7][lm] = (double)a1.w;
    if (emitH) {
      ushort4 o0, o1;
      o0.x = f2bf(a0.x); o0.y = f2bf(a0.y); o0.z = f2bf(a0.z); o0.w = f2bf(a0.w);
      o1.x = f2bf(a1.x); o1.y = f2bf(a1.y); o1.z = f2bf(a1.z); o1.w = f2bf(a1.w);
      *(ushort4*)&Hb[(size_t)(m0 + lm) * Dn + k0 + lk8] = o0;
      *(ushort4*)&Hb[(size_t)(m0 + lm) * Dn + k0 + lk8 + 4] = o1;
    }
    float4 b0 = *(const float4*)&B[(size_t)(k0 + br) * En + n0 + bc];
    float4 b1 = *(const float4*)&B[(size_t)(k0 + br) * En + n0 + bc + 4];
    Bsd[br][bc + 0] = (double)b0.x; Bsd[br][bc + 1] = (double)b0.y;
    Bsd[br][bc + 2] = (double)b0.z; Bsd[br][bc + 3] = (double)b0.w;
    Bsd[br][bc + 4] = (double)b1.x; Bsd[br][bc + 5] = (double)b1.y;
    Bsd[br][bc + 6] = (double)b1.z; Bsd[br][bc + 7] = (double)b1.w;
    __syncthreads();
#pragma unroll
    for (int kk = 0; kk < 32; ++kk) {
      double a[4], b[4];
#pragma unroll
      for (int i = 0; i < 4; ++i) a[i] = Asd[kk][ty + 16 * i];
#pragma unroll
      for (int j = 0; j < 4; ++j) b[j] = Bsd[kk][tx + 16 * j];
#pragma unroll
      for (int i = 0; i < 4; ++i)
#pragma unroll
        for (int j = 0; j < 4; ++j)
          acc[i][j] += a[i] * b[j];
    }
    __syncthreads();
  }
  double* prow = part + (size_t)blockIdx.z * T0n * En;
#pragma unroll
  for (int i = 0; i < 4; ++i) {
    int row = m0 + ty + 16 * i;
#pragma unroll
    for (int j = 0; j < 4; ++j)
      prow[(size_t)row * En + n0 + tx + 16 * j] = acc[i][j];
  }
}

// ---------------------------------------------------------------------------
// Top-8: one wave per token, shuffle butterfly. Sums KSPLIT fp64 partials.
// ---------------------------------------------------------------------------
__global__ __launch_bounds__(256) void k_topk(
    const double* __restrict__ part, int* __restrict__ sel,
    float* __restrict__ rw, int* __restrict__ cnt_e) {
  const int wid = threadIdx.x >> 6, ln = threadIdx.x & 63;
  const int t = blockIdx.x * 4 + wid;

  double v[4];
#pragma unroll
  for (int j = 0; j < 4; ++j) {
    double s = 0.0;
#pragma unroll
    for (int kc = 0; kc < KSPLIT; ++kc)
      s += part[((size_t)kc * T0n + t) * En + ln + 64 * j];
    v[j] = s;
  }

  float topv[8];
  int topi[8];
#pragma unroll
  for (int k = 0; k < 8; ++k) {
    double bv = v[0]; int bi = ln;
#pragma unroll
    for (int j = 1; j < 4; ++j) {
      int cand = ln + 64 * j;
      if (v[j] > bv || (v[j] == bv && cand < bi)) { bv = v[j]; bi = cand; }
    }
#pragma unroll
    for (int off = 32; off > 0; off >>= 1) {
      double ov = __shfl_xor(bv, off);
      int oi = __shfl_xor(bi, off);
      if (ov > bv || (ov == bv && oi < bi)) { bv = ov; bi = oi; }
    }
    topv[k] = (float)bv; topi[k] = bi;
    if ((bi & 63) == ln) v[bi >> 6] = -1e300;
  }

  if (ln < 8) {
    float m = topv[0];
    float ssum = 0.f;
#pragma unroll
    for (int k = 0; k < 8; ++k) ssum += expf(topv[k] - m);
    rw[t * 8 + ln] = expf(topv[ln] - m) / ssum;
    sel[t * 8 + ln] = topi[ln];
    atomicAdd(&cnt_e[topi[ln]], 1);
  }
}

// Parallel per-group prefix over 256 experts.
__global__ __launch_bounds__(256) void k_scan(
    const int* __restrict__ cnt_e, int* __restrict__ off_e,
    int* __restrict__ cur_e, int* __restrict__ grp_n) {
  __shared__ int c[256];
  int tid = threadIdx.x;
  c[tid] = cnt_e[tid];
  __syncthreads();
  int g = tid >> 5, ei = tid & 31;
  int run = 0;
  for (int i = 0; i < ei; ++i) run += c[(g << 5) + i];
  off_e[tid] = g * SEGCAP + run;
  cur_e[tid] = g * SEGCAP + run;
  if (ei == 31) grp_n[g] = run + c[tid];
}

__global__ void k_scatter(const int* __restrict__ sel, int* __restrict__ cur_e,
                          int* __restrict__ rseg) {
  int i = blockIdx.x * 256 + threadIdx.x;
  int e = sel[i];
  int pos = atomicAdd(&cur_e[e], 1);
  rseg[pos] = i;
}

// ---------------------------------------------------------------------------
// h1 = H @ A_fac[g]. 512 threads: waves 0-3 gate, 4-7 up. H read as bf16
// (Hb, router side-channel; 8.4 MB total -> L2-resident across the 8 group
// re-reads). Output bf16. grid (T0/64, G).
// ---------------------------------------------------------------------------
__global__ __launch_bounds__(512) void k_h1_mfma(
    const unsigned short* __restrict__ Hb,
    const unsigned short* __restrict__ AgT, const unsigned short* __restrict__ AuT,
    unsigned short* __restrict__ h1gb, unsigned short* __restrict__ h1ub) {
  const int t0 = blockIdx.x * 64;
  const int g = blockIdx.y;
  const unsigned short* Wg = AgT + (size_t)g * Rn * Dn;
  const unsigned short* Wu = AuT + (size_t)g * Rn * Dn;

  __shared__ unsigned short As[64 * 72];
  __shared__ unsigned short Bg_l[64 * 72];
  __shared__ unsigned short Bu_l[64 * 72];
  const int tid = threadIdx.x;
  const int w = tid >> 6, ln = tid & 63;
  const int path = w >> 2, ws = w & 3;
  const int quad = ln >> 4, lane16 = ln & 15;
  const int j = tid >> 3, q = (tid & 7) * 8;   // 64 rows x 8 chunks

  f4v S[4] = {};

  for (int k0 = 0; k0 < Dn; k0 += 64) {
    *(uint4*)&As[j * 72 + q]   = *(const uint4*)&Hb[(size_t)(t0 + j) * Dn + k0 + q];
    *(uint4*)&Bg_l[j * 72 + q] = *(const uint4*)&Wg[(size_t)j * Dn + k0 + q];
    *(uint4*)&Bu_l[j * 72 + q] = *(const uint4*)&Wu[(size_t)j * Dn + k0 + q];
    __syncthreads();
    const unsigned short* Bl = path ? Bu_l : Bg_l;
#pragma unroll
    for (int kk = 0; kk < 2; ++kk) {
      s8v a = *(const s8v*)&As[(ws * 16 + lane16) * 72 + kk * 32 + quad * 8];
#pragma unroll
      for (int nt = 0; nt < 4; ++nt) {
        s8v b = *(const s8v*)&Bl[(nt * 16 + lane16) * 72 + kk * 32 + quad * 8];
        S[nt] = MFMA16(a, b, S[nt]);
      }
    }
    __syncthreads();
  }
  unsigned short* out = path ? h1ub : h1gb;
#pragma unroll
  for (int nt = 0; nt < 4; ++nt)
#pragma unroll
    for (int r = 0; r < 4; ++r) {
      int row = t0 + ws * 16 + quad * 4 + r;
      int col = g * 64 + nt * 16 + lane16;
      out[(size_t)row * (Gn * Rn) + col] = f2bf(S[nt][r]);
    }
}

// ---------------------------------------------------------------------------
// Per-expert core (gate/up) via MFMA. 512 threads: waves 0-3 gate, 4-7 up.
// C_e (fp32, read once by this single block) transposed+converted in-kernel.
// ---------------------------------------------------------------------------
__global__ __launch_bounds__(512) void k_core_gu(
    const unsigned short* __restrict__ h1gb, const unsigned short* __restrict__ h1ub,
    const float* __restrict__ Cgate, const float* __restrict__ Cup,
    const int* __restrict__ rseg, const int* __restrict__ off_e,
    const int* __restrict__ cnt_e,
    unsigned short* __restrict__ h2gb, unsigned short* __restrict__ h2ub) {
  const int e = blockIdx.x;
  const int ne = cnt_e[e];
  if (ne == 0) return;
  const int g = e >> 5;
  const int base = off_e[e];
  __shared__ unsigned short Cg_l[64 * 72];
  __shared__ unsigned short Cu_l[64 * 72];
  __shared__ unsigned short Ags[64 * 72];
  __shared__ unsigned short Aus[64 * 72];
  __shared__ int rids[64];
  const int tid = threadIdx.x;
  const int w = tid >> 6, ln = tid & 63;
  const int path = w >> 2, ws = w & 3;
  const int quad = ln >> 4, lane16 = ln & 15;
  const int j = tid >> 3, q = (tid & 7) * 8;
  {
    // load C[k][n] fp32, store transposed bf16 [n][k] (one-time)
    const float* cg = Cgate + (size_t)e * (Rn * Rn);
    const float* cu = Cup   + (size_t)e * (Rn * Rn);
    float4 g0 = *(const float4*)&cg[j * 64 + q];
    float4 g1 = *(const float4*)&cg[j * 64 + q + 4];
    float4 u0 = *(const float4*)&cu[j * 64 + q];
    float4 u1 = *(const float4*)&cu[j * 64 + q + 4];
    Cg_l[(q + 0) * 72 + j] = f2bf(g0.x); Cg_l[(q + 1) * 72 + j] = f2bf(g0.y);
    Cg_l[(q + 2) * 72 + j] = f2bf(g0.z); Cg_l[(q + 3) * 72 + j] = f2bf(g0.w);
    Cg_l[(q + 4) * 72 + j] = f2bf(g1.x); Cg_l[(q + 5) * 72 + j] = f2bf(g1.y);
    Cg_l[(q + 6) * 72 + j] = f2bf(g1.z); Cg_l[(q + 7) * 72 + j] = f2bf(g1.w);
    Cu_l[(q + 0) * 72 + j] = f2bf(u0.x); Cu_l[(q + 1) * 72 + j] = f2bf(u0.y);
    Cu_l[(q + 2) * 72 + j] = f2bf(u0.z); Cu_l[(q + 3) * 72 + j] = f2bf(u0.w);
    Cu_l[(q + 4) * 72 + j] = f2bf(u1.x); Cu_l[(q + 5) * 72 + j] = f2bf(u1.y);
    Cu_l[(q + 6) * 72 + j] = f2bf(u1.z); Cu_l[(q + 7) * 72 + j] = f2bf(u1.w);
  }
  const int ntile = (ne + 63) >> 6;
  for (int it = 0; it < ntile; ++it) {
    int mi = it * 64 + j;
    int rid = (mi < ne) ? rseg[base + mi] : -1;
    if ((tid & 7) == 0) rids[j] = rid;
    uint4 zg = {0, 0, 0, 0}, zu = {0, 0, 0, 0};
    if (rid >= 0) {
      zg = *(const uint4*)&h1gb[(size_t)(rid >> 3) * (Gn * Rn) + g * 64 + q];
      zu = *(const uint4*)&h1ub[(size_t)(rid >> 3) * (Gn * Rn) + g * 64 + q];
    }
    *(uint4*)&Ags[j * 72 + q] = zg;
    *(uint4*)&Aus[j * 72 + q] = zu;
    __syncthreads();
    const unsigned short* Al = path ? Aus : Ags;
    const unsigned short* Cl = path ? Cu_l : Cg_l;
    f4v S[4] = {};
#pragma unroll
    for (int kk = 0; kk < 2; ++kk) {
      s8v a = *(const s8v*)&Al[(ws * 16 + lane16) * 72 + kk * 32 + quad * 8];
#pragma unroll
      for (int nt = 0; nt < 4; ++nt) {
        s8v b = *(const s8v*)&Cl[(nt * 16 + lane16) * 72 + kk * 32 + quad * 8];
        S[nt] = MFMA16(a, b, S[nt]);
      }
    }
    unsigned short* out = path ? h2ub : h2gb;
#pragma unroll
    for (int nt = 0; nt < 4; ++nt)
#pragma unroll
      for (int r = 0; r < 4; ++r) {
        int rid2 = rids[ws * 16 + quad * 4 + r];
        if (rid2 >= 0)
          out[(size_t)rid2 * 64 + nt * 16 + lane16] = f2bf(S[nt][r]);
      }
    __syncthreads();
  }
}

// ---------------------------------------------------------------------------
// Fused expand + down-A via MFMA (inter stays on-chip). 128-row tiles.
// grid (4 I-splits, NROWS/128, G).
// ---------------------------------------------------------------------------
__global__ __launch_bounds__(256) void k_expand_mfma(
    const unsigned short* __restrict__ h2gb, const unsigned short* __restrict__ h2ub,
    const unsigned short* __restrict__ BgT, const unsigned short* __restrict__ BuT,
    const unsigned short* __restrict__ AdT,
    const int* __restrict__ rseg, const int* __restrict__ grp_n,
    float* __restrict__ h1d) {
  const int g = blockIdx.z;
  const int ng = grp_n[g];
  const int m0 = blockIdx.y * 128;
  if (m0 >= ng) return;
  const int c_beg = blockIdx.x * 6;
  const int c_end = min(22, c_beg + 6);

  __shared__ unsigned short Hg_l[128 * 72];
  __shared__ unsigned short Hu_l[128 * 72];
  __shared__ unsigned short Bg_l[64 * 72];   // B_gate chunk, then inter rows 0..63
  __shared__ unsigned short Bu_l[64 * 72];   // B_up chunk, then inter rows 64..127
  __shared__ unsigned short Ad_l[64 * 72];
  __shared__ int rids[128];

  const int tid = threadIdx.x;
  const int w = tid >> 6, ln = tid & 63;
  const int quad = ln >> 4, lane16 = ln & 15;

  if (tid < 128) rids[tid] = (m0 + tid < ng) ? rseg[g * SEGCAP + m0 + tid] : -1;
  __syncthreads();
#pragma unroll
  for (int i = 0; i < 4; ++i) {
    int c = tid + i * 256;
    int row = c >> 3, cc = (c & 7) * 8;
    int rid = rids[row];
    uint4 zg = {0, 0, 0, 0}, zu = {0, 0, 0, 0};
    if (rid >= 0) {
      zg = *(const uint4*)&h2gb[(size_t)rid * 64 + cc];
      zu = *(const uint4*)&h2ub[(size_t)rid * 64 + cc];
    }
    *(uint4*)&Hg_l[row * 72 + cc] = zg;
    *(uint4*)&Hu_l[row * 72 + cc] = zu;
  }

  const unsigned short* Bg_base = BgT + (size_t)g * In * Rn;
  const unsigned short* Bu_base = BuT + (size_t)g * In * Rn;
  const unsigned short* Ad_base = AdT + (size_t)g * Rn * In;

  f4v P[2][4] = {};

  for (int c = c_beg; c < c_end; ++c) {
    const int i0 = c * 64;
#pragma unroll
    for (int i = 0; i < 2; ++i) {
      int cq = tid + i * 256;
      int row = cq >> 3, co = (cq & 7) * 8;
      *(uint4*)&Bg_l[row * 72 + co] = *(const uint4*)&Bg_base[(size_t)(i0 + row) * Rn + co];
      *(uint4*)&Bu_l[row * 72 + co] = *(const uint4*)&Bu_base[(size_t)(i0 + row) * Rn + co];
      *(uint4*)&Ad_l[row * 72 + co] = *(const uint4*)&Ad_base[(size_t)row * In + i0 + co];
    }
    __syncthreads();

    f4v Sg[2][4] = {}, Su[2][4] = {};
#pragma unroll
    for (int kk = 0; kk < 2; ++kk) {
      s8v ag[2], au[2], bg[4], bu[4];
#pragma unroll
      for (int mt = 0; mt < 2; ++mt) {
        ag[mt] = *(const s8v*)&Hg_l[(w * 32 + mt * 16 + lane16) * 72 + kk * 32 + quad * 8];
        au[mt] = *(const s8v*)&Hu_l[(w * 32 + mt * 16 + lane16) * 72 + kk * 32 + quad * 8];
      }
#pragma unroll
      for (int nt = 0; nt < 4; ++nt) {
        bg[nt] = *(const s8v*)&Bg_l[(nt * 16 + lane16) * 72 + kk * 32 + quad * 8];
        bu[nt] = *(const s8v*)&Bu_l[(nt * 16 + lane16) * 72 + kk * 32 + quad * 8];
      }
#pragma unroll
      for (int mt = 0; mt < 2; ++mt)
#pragma unroll
        for (int nt = 0; nt < 4; ++nt) {
          Sg[mt][nt] = MFMA16(ag[mt], bg[nt], Sg[mt][nt]);
          Su[mt][nt] = MFMA16(au[mt], bu[nt], Su[mt][nt]);
        }
    }
    __syncthreads();   // Bg_l/Bu_l reads done; reuse as inter
    {
      unsigned short* ibuf = (w < 2) ? Bg_l : Bu_l;   // rows 0..63 / 64..127
#pragma unroll
      for (int mt = 0; mt < 2; ++mt)
#pragma unroll
        for (int nt = 0; nt < 4; ++nt)
#pragma unroll
          for (int r = 0; r < 4; ++r) {
            float sg = Sg[mt][nt][r];
            float v = sg / (1.f + __expf(-sg)) * Su[mt][nt][r];
            int row = (w * 32 + mt * 16 + quad * 4 + r) & 63;
            ibuf[row * 72 + nt * 16 + lane16] = f2bf(v);
          }
    }
    __syncthreads();
#pragma unroll
    for (int kk = 0; kk < 2; ++kk) {
      s8v ai[2], bd[4];
#pragma unroll
      for (int mt = 0; mt < 2; ++mt) {
        const unsigned short* src = (w < 2) ? Bg_l : Bu_l;
        int arow = (w * 32 + mt * 16 + lane16) & 63;
        ai[mt] = *(const s8v*)&src[arow * 72 + kk * 32 + quad * 8];
      }
#pragma unroll
      for (int nt = 0; nt < 4; ++nt)
        bd[nt] = *(const s8v*)&Ad_l[(nt * 16 + lane16) * 72 + kk * 32 + quad * 8];
#pragma unroll
      for (int mt = 0; mt < 2; ++mt)
#pragma unroll
        for (int nt = 0; nt < 4; ++nt)
          P[mt][nt] = MFMA16(ai[mt], bd[nt], P[mt][nt]);
    }
    __syncthreads();
  }

#pragma unroll
  for (int mt = 0; mt < 2; ++mt)
#pragma unroll
    for (int nt = 0; nt < 4; ++nt)
#pragma unroll
      for (int r = 0; r < 4; ++r) {
        int lrow = w * 32 + mt * 16 + quad * 4 + r;
        int rid = rids[lrow];
        if (rid >= 0)
          atomicAdd(&h1d[(size_t)rid * 64 + nt * 16 + lane16], P[mt][nt][r]);
      }
}

// ---------------------------------------------------------------------------
// Per-expert down core via MFMA + routing weight, reduce to y[t,g,64].
// 512 threads: 128 rows/iter. C_down transposed+converted in-kernel.
// ---------------------------------------------------------------------------
__global__ __launch_bounds__(512) void k_core_down(
    const float* __restrict__ h1d, const float* __restrict__ Cdown,
    const float* __restrict__ rw,
    const int* __restrict__ rseg, const int* __restrict__ off_e,
    const int* __restrict__ cnt_e,
    float* __restrict__ y) {
  const int e = blockIdx.x;
  const int ne = cnt_e[e];
  if (ne == 0) return;
  const int g = e >> 5;
  const int base = off_e[e];
  __shared__ unsigned short Bd_l[64 * 72];
  __shared__ unsigned short Ad_l[128 * 72];
  __shared__ int rids[128];
  const int tid = threadIdx.x;
  const int w = tid >> 6, ln = tid & 63;
  const int quad = ln >> 4, lane16 = ln & 15;
  {
    int j = tid >> 3, q = (tid & 7) * 8;
    const float* cd = Cdown + (size_t)e * (Rn * Rn);
    float4 d0 = *(const float4*)&cd[j * 64 + q];
    float4 d1 = *(const float4*)&cd[j * 64 + q + 4];
    Bd_l[(q + 0) * 72 + j] = f2bf(d0.x); Bd_l[(q + 1) * 72 + j] = f2bf(d0.y);
    Bd_l[(q + 2) * 72 + j] = f2bf(d0.z); Bd_l[(q + 3) * 72 + j] = f2bf(d0.w);
    Bd_l[(q + 4) * 72 + j] = f2bf(d1.x); Bd_l[(q + 5) * 72 + j] = f2bf(d1.y);
    Bd_l[(q + 6) * 72 + j] = f2bf(d1.z); Bd_l[(q + 7) * 72 + j] = f2bf(d1.w);
  }
  const int gj = tid >> 2, gq = (tid & 3) * 16;   // 128 rows x 4 chunks of 16
  const int ntile = (ne + 127) >> 7;
  for (int it = 0; it < ntile; ++it) {
    int mi = it * 128 + gj;
    int rid = (mi < ne) ? rseg[base + mi] : -1;
    if ((tid & 3) == 0) rids[gj] = rid;
#pragma unroll
    for (int i = 0; i < 4; ++i) {
      int kb = gq + i * 4;
      float4 vd = {0.f, 0.f, 0.f, 0.f};
      if (rid >= 0) vd = *(const float4*)&h1d[(size_t)rid * 64 + kb];
      ushort4 od;
      od.x = f2bf(vd.x); od.y = f2bf(vd.y); od.z = f2bf(vd.z); od.w = f2bf(vd.w);
      *(ushort4*)&Ad_l[gj * 72 + kb] = od;
    }
    __syncthreads();
    f4v Sd[4] = {};
#pragma unroll
    for (int kk = 0; kk < 2; ++kk) {
      s8v ad = *(const s8v*)&Ad_l[(w * 16 + lane16) * 72 + kk * 32 + quad * 8];
#pragma unroll
      for (int nt = 0; nt < 4; ++nt) {
        s8v bd = *(const s8v*)&Bd_l[(nt * 16 + lane16) * 72 + kk * 32 + quad * 8];
        Sd[nt] = MFMA16(ad, bd, Sd[nt]);
      }
    }
#pragma unroll
    for (int nt = 0; nt < 4; ++nt)
#pragma unroll
      for (int r = 0; r < 4; ++r) {
        int rid2 = rids[w * 16 + quad * 4 + r];
        if (rid2 >= 0) {
          float wgt = rw[rid2];
          atomicAdd(&y[(size_t)(rid2 >> 3) * (Gn * Rn) + g * 64 + nt * 16 + lane16],
                    wgt * Sd[nt][r]);
        }
      }
    __syncthreads();
  }
}

// ---------------------------------------------------------------------------
// Combine: out[2048,2048] = y[2048,512] @ B_down-as-[512,2048], MFMA bf16.
// ---------------------------------------------------------------------------
__global__ __launch_bounds__(256) void k_combine(
    const float* __restrict__ y, const unsigned short* __restrict__ BdT,
    float* __restrict__ outp) {
  const int t0 = blockIdx.y * 128, n0 = blockIdx.x * 128;
  __shared__ unsigned short As[128 * 72];
  __shared__ unsigned short Bs[128 * 72];
  const int tid = threadIdx.x;
  const int w = tid >> 6, ln = tid & 63;
  const int quad = ln >> 4, lane16 = ln & 15;
  const int mbase = (w >> 1) * 64, nbase = (w & 1) * 64;

  f4v acc[4][4] = {};

  for (int k0 = 0; k0 < Gn * Rn; k0 += 64) {
#pragma unroll
    for (int i = 0; i < 8; ++i) {
      int c = tid + i * 256;
      int row = c >> 4, cc = (c & 15) * 4;
      float4 v = *(const float4*)&y[(size_t)(t0 + row) * (Gn * Rn) + k0 + cc];
      ushort4 o;
      o.x = f2bf(v.x); o.y = f2bf(v.y); o.z = f2bf(v.z); o.w = f2bf(v.w);
      *(ushort4*)&As[row * 72 + cc] = o;
    }
#pragma unroll
    for (int i = 0; i < 4; ++i) {
      int c = tid + i * 256;
      int row = c >> 3, cc = (c & 7) * 8;
      *(uint4*)&Bs[row * 72 + cc] = *(const uint4*)&BdT[(size_t)(n0 + row) * (Gn * Rn) + k0 + cc];
    }
    __syncthreads();
#pragma unroll
    for (int kk = 0; kk < 2; ++kk) {
      s8v a[4], b[4];
#pragma unroll
      for (int mt = 0; mt < 4; ++mt)
        a[mt] = *(const s8v*)&As[(mbase + mt * 16 + lane16) * 72 + kk * 32 + quad * 8];
#pragma unroll
      for (int nt = 0; nt < 4; ++nt)
        b[nt] = *(const s8v*)&Bs[(nbase + nt * 16 + lane16) * 72 + kk * 32 + quad * 8];
#pragma unroll
      for (int mt = 0; mt < 4; ++mt)
#pragma unroll
        for (int nt = 0; nt < 4; ++nt)
          acc[mt][nt] = MFMA16(a[mt], b[nt], acc[mt][nt]);
    }
    __syncthreads();
  }
#pragma unroll
  for (int mt = 0; mt < 4; ++mt)
#pragma unroll
    for (int nt = 0; nt < 4; ++nt)
#pragma unroll
      for (int r = 0; r < 4; ++r)
        outp[(size_t)(t0 + mbase + mt * 16 + quad * 4 + r) * Dn +
             n0 + nbase + nt * 16 + lane16] = acc[mt][nt][r];
}

// ---------------------------------------------------------------------------
extern "C" void kernel_launch(void* const* d_in, const int* in_sizes, int n_in,
                              void* d_out, int out_size, void* d_ws, size_t ws_size,
                              hipStream_t stream) {
  const float* hidden = (const float*)d_in[0];
  const float* w_gate = (const float*)d_in[1];
  const float* A_gate = (const float*)d_in[2];
  const float* C_gate = (const float*)d_in[3];
  const float* B_gate = (const float*)d_in[4];
  const float* A_up   = (const float*)d_in[5];
  const float* C_up   = (const float*)d_in[6];
  const float* B_up   = (const float*)d_in[7];
  const float* A_down = (const float*)d_in[8];
  const float* C_down = (const float*)d_in[9];
  const float* B_down = (const float*)d_in[10];
  float* out = (float*)d_out;

  // Workspace layout. part = fp64 router partials, KSPLIT=4 ->
  // 4*2048*256*8 = 16,777,216 B at offset 0. The six buffers below sum to
  // EXACTLY 16,777,216 B and are all written only AFTER k_topk consumes part
  // (stream-ordered) -> aliasing safe. Hb onwards is outside the part region
  // (Hb is written BY the router while part is live). Total ws ~36.4 MB.
  char* base = (char*)d_ws;
  double* part = (double*)d_ws;
  size_t o = 0;
  unsigned short* h2gb = (unsigned short*)(base + o); o += (size_t)NROWS * Rn * 2;
  unsigned short* h2ub = (unsigned short*)(base + o); o += (size_t)NROWS * Rn * 2;
  unsigned short* h1gb = (unsigned short*)(base + o); o += (size_t)T0n * Gn * Rn * 2;
  unsigned short* h1ub = (unsigned short*)(base + o); o += (size_t)T0n * Gn * Rn * 2;
  float* h1d = (float*)(base + o); o += (size_t)NROWS * Rn * 4;
  float* y   = (float*)(base + o); o += (size_t)T0n * Gn * Rn * 4;   // o = 16,777,216
  unsigned short* Hb  = (unsigned short*)(base + o); o += (size_t)T0n * Dn * 2;
  unsigned short* AgT = (unsigned short*)(base + o); o += (size_t)Gn * Rn * Dn * 2;
  unsigned short* AuT = (unsigned short*)(base + o); o += (size_t)Gn * Rn * Dn * 2;
  unsigned short* BgT = (unsigned short*)(base + o); o += (size_t)Gn * In * Rn * 2;
  unsigned short* BuT = (unsigned short*)(base + o); o += (size_t)Gn * In * Rn * 2;
  unsigned short* AdT = (unsigned short*)(base + o); o += (size_t)Gn * Rn * In * 2;
  unsigned short* BdT = (unsigned short*)(base + o); o += (size_t)Dn * Gn * Rn * 2;
  float* rwp = (float*)(base + o); o += (size_t)NROWS * 4;
  int* sel   = (int*)(base + o); o += (size_t)NROWS * 4;
  int* rseg  = (int*)(base + o); o += (size_t)Gn * SEGCAP * 4;
  int* cnt_e = (int*)(base + o); o += En * 4;
  int* off_e = (int*)(base + o); o += En * 4;
  int* cur_e = (int*)(base + o); o += En * 4;
  int* grp_n = (int*)(base + o); o += Gn * 4;

  hipMemsetAsync(cnt_e, 0, En * sizeof(int), stream);

  // 1) router partials (fp64 LDS conflict-free, fp64 regs, split-K=4)
  //    + Hb bf16 side-channel
  k_router_part<<<dim3(En / 64, T0n / 64, KSPLIT), 256, 0, stream>>>(
      hidden, w_gate, part, Hb);
  // 2) top-8 + renorm + expert counts
  k_topk<<<T0n / 4, 256, 0, stream>>>(part, sel, rwp, cnt_e);
  // 3) offsets (parallel prefix) + scatter rows by expert
  k_scan<<<1, 256, 0, stream>>>(cnt_e, off_e, cur_e, grp_n);
  k_scatter<<<NROWS / 256, 256, 0, stream>>>(sel, cur_e, rseg);

  // part is now dead; aliased buffers may be written. h1d and y are adjacent.
  hipMemsetAsync(h1d, 0, (size_t)(NROWS * Rn + T0n * Gn * Rn) * sizeof(float), stream);

  // 4) transpose+convert the 6 shared weight tensors to bf16 operand layouts
  {
    TD6 D;
    D.t[0] = {A_gate, AgT, Dn, Rn, Rn / 32, (Rn / 32) * (Dn / 32), 0};
    D.t[1] = {A_up,   AuT, Dn, Rn, Rn / 32, (Rn / 32) * (Dn / 32), 1024};
    D.t[2] = {B_gate, BgT, Rn, In, In / 32, (In / 32) * (Rn / 32), 2048};
    D.t[3] = {B_up,   BuT, Rn, In, In / 32, (In / 32) * (Rn / 32), 2752};
    D.t[4] = {A_down, AdT, In, Rn, Rn / 32, (Rn / 32) * (In / 32), 3456};
    D.t[5] = {B_down, BdT, Gn * Rn, Dn, Dn / 32, (Dn / 32) * (Gn * Rn / 32), 4160};
    k_tcvt6<<<5184, 256, 0, stream>>>(D);
  }

  // 5) dense in-factor projections (512 thr, Hb bf16 input)
  k_h1_mfma<<<dim3(T0n / 64, Gn), 512, 0, stream>>>(Hb, AgT, AuT, h1gb, h1ub);
  // 6) per-expert core (gate/up) via MFMA (512 thr, in-kernel C transpose)
  k_core_gu<<<En, 512, 0, stream>>>(h1gb, h1ub, C_gate, C_up,
                                    rseg, off_e, cnt_e, h2gb, h2ub);
  // 7) fused expand + down-A (MFMA; inter stays on-chip), 128-row tiles
  k_expand_mfma<<<dim3(4, NROWS / 128, Gn), 256, 0, stream>>>(
      h2gb, h2ub, BgT, BuT, AdT, rseg, grp_n, h1d);
  // 8) per-expert down core via MFMA + rw (512 thr, in-kernel C transpose)
  k_core_down<<<En, 512, 0, stream>>>(h1d, C_down, rwp,
                                      rseg, off_e, cnt_e, y);
  // 9) combine (MFMA bf16)
  k_combine<<<dim3(Dn / 128, T0n / 128), 256, 0, stream>>>(y, BdT, out);
}